// Round 1
// baseline (1438.602 us; speedup 1.0000x reference)
//
#include <hip/hip_runtime.h>
#include <math.h>

#define B_ 4
#define C_ 512
#define T_ 8
#define L_ 512
#define H_ 8
#define HD_ 64

// ---------------------------------------------------------------------------
// Workspace layout (floats):
//   pooled : [0, 16384)                       (B*T, C)
//   gw     : [16384, 16640)                   (B*T, H)
//   qT     : [16640, +8388608)                (B*T, C, L)   q^T per bt
//   kvT    : next 16777216                    (B*T, 2C, L)  rows [0,512)=k, [512,1024)=v
//   oT     : next 8388608                     (B*T, C, L)   attention out^T
// total = 134,284,288 bytes
// ---------------------------------------------------------------------------

// pooled[b,t,c] = mean_l e[b,c,t,l].  One wave per row (512 contiguous floats).
__global__ __launch_bounds__(256) void pool_kernel(const float* __restrict__ e,
                                                   float* __restrict__ pooled) {
  int wave = threadIdx.x >> 6;
  int lane = threadIdx.x & 63;
  int r = blockIdx.x * 4 + wave;          // r = (b*C + c)*T + t
  int t = r % T_;
  int c = (r / T_) % C_;
  int b = r / (T_ * C_);
  const float* row = e + (size_t)r * L_;
  float s = 0.f;
#pragma unroll
  for (int i = 0; i < L_ / 64; ++i) s += row[lane + i * 64];
#pragma unroll
  for (int off = 32; off > 0; off >>= 1) s += __shfl_down(s, off, 64);
  if (lane == 0) pooled[(b * T_ + t) * C_ + c] = s * (1.0f / L_);
}

// gw[b,t,h] = softmax_h( tanh(pooled @ Wg1^T + bg1) @ Wg2^T + bg2 )
__global__ __launch_bounds__(256) void gate_kernel(const float* __restrict__ pooled,
                                                   const float* __restrict__ Wg1,
                                                   const float* __restrict__ bg1,
                                                   const float* __restrict__ Wg2,
                                                   const float* __restrict__ bg2,
                                                   float* __restrict__ gw) {
  __shared__ float ps[C_];
  __shared__ float h1[C_];
  __shared__ float part[256];
  __shared__ float glog_s[H_];
  int bt = blockIdx.x;
  int tid = threadIdx.x;
  ps[tid] = pooled[bt * C_ + tid];
  ps[tid + 256] = pooled[bt * C_ + tid + 256];
  __syncthreads();
  for (int cp = tid; cp < C_; cp += 256) {
    float acc = bg1[cp];
    const float* wrow = Wg1 + (size_t)cp * C_;
    for (int c = 0; c < C_; ++c) acc += wrow[c] * ps[c];
    h1[cp] = tanhf(acc);
  }
  __syncthreads();
  int h = tid >> 5, s = tid & 31;
  float p = 0.f;
  const float* w2 = Wg2 + (size_t)h * C_;
  for (int c = s; c < C_; c += 32) p += w2[c] * h1[c];
  part[tid] = p;
  __syncthreads();
  if (tid < H_) {
    float acc = bg2[tid];
    for (int i = 0; i < 32; ++i) acc += part[tid * 32 + i];
    glog_s[tid] = acc;
  }
  __syncthreads();
  if (tid == 0) {
    float m = -1e30f;
    for (int i = 0; i < H_; ++i) m = fmaxf(m, glog_s[i]);
    float sum = 0.f;
    float ex[H_];
    for (int i = 0; i < H_; ++i) { ex[i] = expf(glog_s[i] - m); sum += ex[i]; }
    for (int i = 0; i < H_; ++i) gw[bt * H_ + i] = ex[i] / sum;
  }
}

// Generic transposed GEMM: Out^T(c',l) = W(c',c) @ X^T(c,l) + bias[c'] (+ resid)
// X^T rows (c) at Xb + c*xRow, contiguous in l.  N=512 cols, K=512.
// Per-bt bases: ptr + b*sB + t*sT.  resid indexed identically to Out.
__global__ __launch_bounds__(256) void gemm512_kernel(
    const float* __restrict__ W, const float* __restrict__ bias,
    const float* __restrict__ X, long xsB, long xsT, long xRow,
    float* __restrict__ Out, long osB, long osT, long oRow,
    const float* __restrict__ resid) {
  __shared__ float As[16][68];   // As[k][i], stride 68 -> float4-aligned rows
  __shared__ float Bs[16][68];   // Bs[k][j]
  int tid = threadIdx.x;
  int tx = tid & 15, ty = tid >> 4;
  int n0 = blockIdx.x * 64;
  int m0 = blockIdx.y * 64;
  int bt = blockIdx.z;
  int b = bt / T_, t = bt % T_;
  const float* Xb = X + (size_t)b * xsB + (size_t)t * xsT;
  float* Ob = Out + (size_t)b * osB + (size_t)t * osT;
  const float* Rb = resid ? resid + (size_t)b * osB + (size_t)t * osT : nullptr;

  float acc[4][4] = {};
  int la_k = tid & 15, la_i = tid >> 4;  // A tile: 64i x 16k
  int lb_j = tid & 63, lb_k = tid >> 6;  // B tile: 16k x 64j

  for (int k0 = 0; k0 < 512; k0 += 16) {
#pragma unroll
    for (int p = 0; p < 4; ++p)
      As[la_k][la_i + p * 16] =
          W[(size_t)(m0 + la_i + p * 16) * 512 + k0 + la_k];
#pragma unroll
    for (int p = 0; p < 4; ++p)
      Bs[lb_k + p * 4][lb_j] =
          Xb[(size_t)(k0 + lb_k + p * 4) * xRow + n0 + lb_j];
    __syncthreads();
#pragma unroll
    for (int kk = 0; kk < 16; ++kk) {
      float4 a4 = *(const float4*)&As[kk][ty * 4];
      float4 b4 = *(const float4*)&Bs[kk][tx * 4];
      float av[4] = {a4.x, a4.y, a4.z, a4.w};
      float bv[4] = {b4.x, b4.y, b4.z, b4.w};
#pragma unroll
      for (int di = 0; di < 4; ++di)
#pragma unroll
        for (int dj = 0; dj < 4; ++dj) acc[di][dj] += av[di] * bv[dj];
    }
    __syncthreads();
  }
#pragma unroll
  for (int di = 0; di < 4; ++di) {
    int i = m0 + ty * 4 + di;
    float bv = bias[i];
    size_t off = (size_t)i * oRow + n0 + tx * 4;
    float4 r;
    r.x = acc[di][0] + bv;
    r.y = acc[di][1] + bv;
    r.z = acc[di][2] + bv;
    r.w = acc[di][3] + bv;
    if (Rb) {
      float4 rr = *(const float4*)(Rb + off);
      r.x += rr.x; r.y += rr.y; r.z += rr.z; r.w += rr.w;
    }
    *(float4*)(Ob + off) = r;
  }
}

// Normalize columns (over hd=64, stride L) of q/k/v head blocks; v also *gw.
// grid: (L/256, 3*H, B*T).  blockIdx.y: which = y/H (0=q,1=k,2=v), h = y%H.
__global__ __launch_bounds__(256) void norm_kernel(float* __restrict__ qT,
                                                   float* __restrict__ kvT,
                                                   const float* __restrict__ gw) {
  int l = blockIdx.x * 256 + threadIdx.x;
  int h = blockIdx.y % H_;
  int which = blockIdx.y / H_;
  int bt = blockIdx.z;
  float* base;
  if (which == 0)       base = qT  + ((size_t)bt * C_ + h * HD_) * L_;
  else if (which == 1)  base = kvT + ((size_t)bt * 2 * C_ + h * HD_) * L_;
  else                  base = kvT + ((size_t)bt * 2 * C_ + C_ + h * HD_) * L_;
  float v[HD_];
  float ss = 0.f;
#pragma unroll
  for (int d = 0; d < HD_; ++d) {
    v[d] = base[(size_t)d * L_ + l];
    ss += v[d] * v[d];
  }
  float scale = 1.0f / fmaxf(sqrtf(ss), 1e-12f);
  if (which == 2) scale *= gw[bt * H_ + h];
#pragma unroll
  for (int d = 0; d < HD_; ++d) base[(size_t)d * L_ + l] = v[d] * scale;
}

// Attention per (bt, h, 32-row i-tile): S rows fully materialized in LDS,
// row softmax, then O = P @ V, epilogue *gw, store to oT (C x L layout).
__global__ __launch_bounds__(256) void attn_kernel(const float* __restrict__ qT,
                                                   const float* __restrict__ kvT,
                                                   const float* __restrict__ gw,
                                                   float* __restrict__ oT) {
  __shared__ float Ks[64][68];     // K/V tile [j][d], 17408 B
  __shared__ float Ss[32][513];    // score rows, 65664 B (513: conflict-free)
  __shared__ float red[32][8];

  int tid = threadIdx.x;
  int i0 = blockIdx.x * 32;
  int h = blockIdx.y;
  int bt = blockIdx.z;

  const float* qb = qT + ((size_t)bt * C_ + h * HD_) * L_;
  const float* kb = kvT + ((size_t)bt * 2 * C_ + h * HD_) * L_;
  const float* vb = kvT + ((size_t)bt * 2 * C_ + C_ + h * HD_) * L_;

  // ---- S = scale * Q K^T : thread owns row ii, strided j ----
  int ii = tid & 31;
  int jsub = tid >> 5;
  float q[HD_];
#pragma unroll
  for (int d = 0; d < HD_; ++d) q[d] = qb[(size_t)d * L_ + i0 + ii];

  for (int jt = 0; jt < 8; ++jt) {
    {
      int jj = tid & 63;
      int d0 = tid >> 6;  // 0..3
#pragma unroll
      for (int p = 0; p < 16; ++p)
        Ks[jj][d0 + p * 4] = kb[(size_t)(d0 + p * 4) * L_ + jt * 64 + jj];
    }
    __syncthreads();
    for (int jj = jsub; jj < 64; jj += 8) {
      float s = 0.f;
#pragma unroll
      for (int d4 = 0; d4 < 16; ++d4) {
        float4 k4 = *(const float4*)&Ks[jj][d4 * 4];
        s += q[d4 * 4 + 0] * k4.x + q[d4 * 4 + 1] * k4.y +
             q[d4 * 4 + 2] * k4.z + q[d4 * 4 + 3] * k4.w;
      }
      Ss[ii][jt * 64 + jj] = s * 0.125f;  // 1/sqrt(64)
    }
    __syncthreads();
  }

  // ---- softmax: 8 threads per row ----
  {
    int row = tid >> 3;
    int seg = tid & 7;
    float m = -1e30f;
#pragma unroll
    for (int j = 0; j < 64; ++j) m = fmaxf(m, Ss[row][seg * 64 + j]);
    red[row][seg] = m;
    __syncthreads();
    float mm = -1e30f;
#pragma unroll
    for (int i = 0; i < 8; ++i) mm = fmaxf(mm, red[row][i]);
    __syncthreads();
    float ssum = 0.f;
#pragma unroll
    for (int j = 0; j < 64; ++j) {
      float ev = __expf(Ss[row][seg * 64 + j] - mm);
      Ss[row][seg * 64 + j] = ev;
      ssum += ev;
    }
    red[row][seg] = ssum;
    __syncthreads();
    float tot = 0.f;
#pragma unroll
    for (int i = 0; i < 8; ++i) tot += red[row][i];
    float inv = 1.0f / tot;
#pragma unroll
    for (int j = 0; j < 64; ++j) Ss[row][seg * 64 + j] *= inv;
  }
  __syncthreads();

  // ---- O = P @ V : thread owns (ii2, 8 consecutive d) ----
  float g = gw[bt * H_ + h];
  int ii2 = tid & 31;
  int db = (tid >> 5) * 8;
  float o[8] = {0, 0, 0, 0, 0, 0, 0, 0};
  for (int jt = 0; jt < 8; ++jt) {
    {
      int jj = tid & 63;
      int d0 = tid >> 6;
#pragma unroll
      for (int p = 0; p < 16; ++p)
        Ks[jj][d0 + p * 4] = vb[(size_t)(d0 + p * 4) * L_ + jt * 64 + jj];
    }
    __syncthreads();
    for (int jj = 0; jj < 64; ++jj) {
      float p = Ss[ii2][jt * 64 + jj];
      float4 v0 = *(const float4*)&Ks[jj][db];
      float4 v1 = *(const float4*)&Ks[jj][db + 4];
      o[0] += p * v0.x; o[1] += p * v0.y; o[2] += p * v0.z; o[3] += p * v0.w;
      o[4] += p * v1.x; o[5] += p * v1.y; o[6] += p * v1.z; o[7] += p * v1.w;
    }
    __syncthreads();
  }
  float* ob = oT + ((size_t)bt * C_ + h * HD_) * L_ + i0 + ii2;
#pragma unroll
  for (int d = 0; d < 8; ++d) ob[(size_t)(db + d) * L_] = o[d] * g;
}

extern "C" void kernel_launch(void* const* d_in, const int* in_sizes, int n_in,
                              void* d_out, int out_size, void* d_ws, size_t ws_size,
                              hipStream_t stream) {
  const float* e   = (const float*)d_in[0];
  const float* x   = (const float*)d_in[1];
  const float* Wq  = (const float*)d_in[2];
  const float* bq  = (const float*)d_in[3];
  const float* Wkv = (const float*)d_in[4];
  const float* bkv = (const float*)d_in[5];
  const float* Wm  = (const float*)d_in[6];
  const float* bm  = (const float*)d_in[7];
  const float* Wg1 = (const float*)d_in[8];
  const float* bg1 = (const float*)d_in[9];
  const float* Wg2 = (const float*)d_in[10];
  const float* bg2 = (const float*)d_in[11];
  float* out = (float*)d_out;

  float* ws = (float*)d_ws;
  float* pooled = ws;                     // 16384
  float* gwp    = ws + 16384;             // 256
  float* qT     = ws + 16640;             // 8388608
  float* kvT    = qT + 8388608;           // 16777216
  float* oT     = kvT + 16777216;         // 8388608

  const long CTL = (long)C_ * T_ * L_;    // 2097152
  const long TCL = (long)T_ * C_ * L_;    // 2097152
  const long CL  = (long)C_ * L_;         // 262144
  const long TL  = (long)T_ * L_;         // 4096

  // 1. pooled mean over L
  pool_kernel<<<dim3(B_ * C_ * T_ / 4), dim3(256), 0, stream>>>(e, pooled);
  // 2. gating softmax
  gate_kernel<<<dim3(B_ * T_), dim3(256), 0, stream>>>(pooled, Wg1, bg1, Wg2,
                                                       bg2, gwp);
  // 3. q^T = Wq @ e^T   (X = e: base b*CTL + t*L, row stride T*L)
  gemm512_kernel<<<dim3(8, 8, B_ * T_), dim3(256), 0, stream>>>(
      Wq, bq, e, CTL, (long)L_, TL, qT, TCL, CL, (long)L_, nullptr);
  // 4. kv^T = Wkv @ x^T  (M = 1024)
  gemm512_kernel<<<dim3(8, 16, B_ * T_), dim3(256), 0, stream>>>(
      Wkv, bkv, x, CTL, (long)L_, TL, kvT, 2 * TCL, 2 * CL, (long)L_, nullptr);
  // 5. normalize q, k; normalize v and * gw
  norm_kernel<<<dim3(L_ / 256, 3 * H_, B_ * T_), dim3(256), 0, stream>>>(qT, kvT,
                                                                         gwp);
  // 6. attention -> oT (already * gw)
  attn_kernel<<<dim3(L_ / 32, H_, B_ * T_), dim3(256), 0, stream>>>(qT, kvT, gwp,
                                                                    oT);
  // 7. out = Wm @ oT + bm + x  (write in (b,c,t,l) layout, row stride T*L)
  gemm512_kernel<<<dim3(8, 8, B_ * T_), dim3(256), 0, stream>>>(
      Wm, bm, oT, TCL, CL, (long)L_, out, CTL, (long)L_, TL, x);
}

// Round 2
// 708.735 us; speedup vs baseline: 2.0298x; 2.0298x over previous
//
#include <hip/hip_runtime.h>
#include <math.h>

#define B_ 4
#define C_ 512
#define T_ 8
#define L_ 512
#define H_ 8
#define HD_ 64

using short8 = __attribute__((ext_vector_type(8))) short;
using f4 = __attribute__((ext_vector_type(4))) float;

// RNE float->bf16 pack (a -> low 16, b -> high 16). Finite inputs only.
__device__ __forceinline__ unsigned pack_bf16(float a, float b) {
  union { float f; unsigned u; } ua, ub;
  ua.f = a; ub.f = b;
  unsigned ra = (ua.u + 0x7FFFu + ((ua.u >> 16) & 1u)) >> 16;
  unsigned rb = (ub.u + 0x7FFFu + ((ub.u >> 16) & 1u)) >> 16;
  return (rb << 16) | (ra & 0xFFFFu);
}

// ---------------------------------------------------------------------------
// Workspace (floats), total 33,571,072 floats = 134,284,288 B (same as R1):
//   pooled [0,16384)  gw [16384,16640)
//   qT   : +8388608          (B*T, C, L) fp32 (raw q projection, un-normalized)
//   kvT  : +16777216         (B*T, 2C, L) fp32;  oT ALIASES its first half
//   Kbf  : +4194304 floats   bf16 [bt][h][l][d]   (normalized k)
//   Vbf  : +4194304 floats   bf16 [bt][h][d][l]   (normalized v * gw)
// ---------------------------------------------------------------------------

__global__ __launch_bounds__(256) void pool_kernel(const float* __restrict__ e,
                                                   float* __restrict__ pooled) {
  int wave = threadIdx.x >> 6;
  int lane = threadIdx.x & 63;
  int r = blockIdx.x * 4 + wave;          // r = (b*C + c)*T + t
  int t = r % T_;
  int c = (r / T_) % C_;
  int b = r / (T_ * C_);
  const float* row = e + (size_t)r * L_;
  float s = 0.f;
#pragma unroll
  for (int i = 0; i < L_ / 64; ++i) s += row[lane + i * 64];
#pragma unroll
  for (int off = 32; off > 0; off >>= 1) s += __shfl_down(s, off, 64);
  if (lane == 0) pooled[(b * T_ + t) * C_ + c] = s * (1.0f / L_);
}

__global__ __launch_bounds__(256) void gate_kernel(const float* __restrict__ pooled,
                                                   const float* __restrict__ Wg1,
                                                   const float* __restrict__ bg1,
                                                   const float* __restrict__ Wg2,
                                                   const float* __restrict__ bg2,
                                                   float* __restrict__ gw) {
  __shared__ float ps[C_];
  __shared__ float h1[C_];
  __shared__ float part[256];
  __shared__ float glog_s[H_];
  int bt = blockIdx.x;
  int tid = threadIdx.x;
  ps[tid] = pooled[bt * C_ + tid];
  ps[tid + 256] = pooled[bt * C_ + tid + 256];
  __syncthreads();
  for (int cp = tid; cp < C_; cp += 256) {
    float acc = bg1[cp];
    const float* wrow = Wg1 + (size_t)cp * C_;
    for (int c = 0; c < C_; ++c) acc += wrow[c] * ps[c];
    h1[cp] = tanhf(acc);
  }
  __syncthreads();
  int h = tid >> 5, s = tid & 31;
  float p = 0.f;
  const float* w2 = Wg2 + (size_t)h * C_;
  for (int c = s; c < C_; c += 32) p += w2[c] * h1[c];
  part[tid] = p;
  __syncthreads();
  if (tid < H_) {
    float acc = bg2[tid];
    for (int i = 0; i < 32; ++i) acc += part[tid * 32 + i];
    glog_s[tid] = acc;
  }
  __syncthreads();
  if (tid == 0) {
    float m = -1e30f;
    for (int i = 0; i < H_; ++i) m = fmaxf(m, glog_s[i]);
    float sum = 0.f;
    float ex[H_];
    for (int i = 0; i < H_; ++i) { ex[i] = expf(glog_s[i] - m); sum += ex[i]; }
    for (int i = 0; i < H_; ++i) gw[bt * H_ + i] = ex[i] / sum;
  }
}

// Out^T(c',l) = W(c',c) @ X^T(c,l) + bias[c'] (+ resid)
__global__ __launch_bounds__(256) void gemm512_kernel(
    const float* __restrict__ W, const float* __restrict__ bias,
    const float* __restrict__ X, long xsB, long xsT, long xRow,
    float* __restrict__ Out, long osB, long osT, long oRow,
    const float* __restrict__ resid) {
  __shared__ float As[16][68];
  __shared__ float Bs[16][68];
  int tid = threadIdx.x;
  int tx = tid & 15, ty = tid >> 4;
  int n0 = blockIdx.x * 64;
  int m0 = blockIdx.y * 64;
  int bt = blockIdx.z;
  int b = bt / T_, t = bt % T_;
  const float* Xb = X + (size_t)b * xsB + (size_t)t * xsT;
  float* Ob = Out + (size_t)b * osB + (size_t)t * osT;
  const float* Rb = resid ? resid + (size_t)b * osB + (size_t)t * osT : nullptr;

  float acc[4][4] = {};
  int la_k = tid & 15, la_i = tid >> 4;
  int lb_j = tid & 63, lb_k = tid >> 6;

  for (int k0 = 0; k0 < 512; k0 += 16) {
#pragma unroll
    for (int p = 0; p < 4; ++p)
      As[la_k][la_i + p * 16] =
          W[(size_t)(m0 + la_i + p * 16) * 512 + k0 + la_k];
#pragma unroll
    for (int p = 0; p < 4; ++p)
      Bs[lb_k + p * 4][lb_j] =
          Xb[(size_t)(k0 + lb_k + p * 4) * xRow + n0 + lb_j];
    __syncthreads();
#pragma unroll
    for (int kk = 0; kk < 16; ++kk) {
      float4 a4 = *(const float4*)&As[kk][ty * 4];
      float4 b4 = *(const float4*)&Bs[kk][tx * 4];
      float av[4] = {a4.x, a4.y, a4.z, a4.w};
      float bv[4] = {b4.x, b4.y, b4.z, b4.w};
#pragma unroll
      for (int di = 0; di < 4; ++di)
#pragma unroll
        for (int dj = 0; dj < 4; ++dj) acc[di][dj] += av[di] * bv[dj];
    }
    __syncthreads();
  }
#pragma unroll
  for (int di = 0; di < 4; ++di) {
    int i = m0 + ty * 4 + di;
    float bv = bias[i];
    size_t off = (size_t)i * oRow + n0 + tx * 4;
    float4 r;
    r.x = acc[di][0] + bv;
    r.y = acc[di][1] + bv;
    r.z = acc[di][2] + bv;
    r.w = acc[di][3] + bv;
    if (Rb) {
      float4 rr = *(const float4*)(Rb + off);
      r.x += rr.x; r.y += rr.y; r.z += rr.z; r.w += rr.w;
    }
    *(float4*)(Ob + off) = r;
  }
}

// Normalize k/v columns (over d, stride L); v *= gw. Emit bf16:
//   K -> Kbf [bt][h][l][d]  (row-per-token, frag-friendly for MFMA A of S^T)
//   V -> Vbf [bt][h][d][l]  (row-per-dim, frag-friendly for MFMA A of PV)
__global__ __launch_bounds__(256) void norm_kernel(const float* __restrict__ kvT,
                                                   const float* __restrict__ gw,
                                                   unsigned short* __restrict__ Kbf,
                                                   unsigned short* __restrict__ Vbf) {
  int l = blockIdx.x * 256 + threadIdx.x;
  int h = blockIdx.y & 7;
  int isv = blockIdx.y >> 3;
  int bt = blockIdx.z;
  const float* base = kvT + ((size_t)bt * 1024 + isv * 512 + h * 64) * 512 + l;
  float v[HD_];
  float ss = 0.f;
#pragma unroll
  for (int d = 0; d < HD_; ++d) {
    v[d] = base[(size_t)d * 512];
    ss += v[d] * v[d];
  }
  float scale = 1.0f / fmaxf(sqrtf(ss), 1e-12f);
  if (isv) scale *= gw[bt * H_ + h];
  if (!isv) {
    unsigned kk[32];
#pragma unroll
    for (int d2 = 0; d2 < 32; ++d2)
      kk[d2] = pack_bf16(v[2 * d2] * scale, v[2 * d2 + 1] * scale);
    uint4* row = (uint4*)(Kbf + (((size_t)bt * H_ + h) * 512 + l) * 64);
#pragma unroll
    for (int c = 0; c < 8; ++c) row[c] = *(uint4*)&kk[4 * c];
  } else {
    unsigned short* col = Vbf + (((size_t)bt * H_ + h) * 64) * 512 + l;
#pragma unroll
    for (int d = 0; d < HD_; ++d)
      col[(size_t)d * 512] = (unsigned short)(pack_bf16(v[d] * scale, 0.f) & 0xFFFFu);
  }
}

// Flash-style MFMA attention. Block = 4 waves, 64 queries (16/wave); loops
// j over 512 in tiles of 64. Per wave: S^T = K.Q^T (C-layout: col=i, row=j),
// online softmax (j spread over quads+regs -> shfl_xor 16/32), P^T shuffled
// into B-operand layout, O^T += V^T.P^T. LDS tiles XOR-swizzled (16B chunks)
// -> conflict-free ds_read_b128 / ds_write_b128.
__global__ __launch_bounds__(256) void attn_kernel(
    const float* __restrict__ qT, const unsigned short* __restrict__ Kbf,
    const unsigned short* __restrict__ Vbf, const float* __restrict__ gw,
    float* __restrict__ oT) {
  __shared__ unsigned short Ka[64 * 64];   // [j][d] bf16, 128B rows, swizzled
  __shared__ unsigned short Va[64 * 64];   // [d][j] bf16, 128B rows, swizzled

  int tid = threadIdx.x;
  int w = tid >> 6;
  int lane = tid & 63;
  int l15 = lane & 15;
  int q = lane >> 4;
  int i0 = blockIdx.x * 64;
  int h = blockIdx.y;
  int bt = blockIdx.z;
  int iglob = i0 + w * 16 + l15;

  // --- load + normalize Q in-register (fold 1/sqrt(hd)=0.125), make B-frags
  const float* qbase = qT + ((size_t)bt * 512 + h * 64) * 512 + iglob;
  float qv[16];
  float ss = 0.f;
#pragma unroll
  for (int ks = 0; ks < 2; ++ks)
#pragma unroll
    for (int t = 0; t < 8; ++t) {
      float val = qbase[(size_t)(ks * 32 + q * 8 + t) * 512];
      qv[ks * 8 + t] = val;
      ss += val * val;
    }
  ss += __shfl_xor(ss, 16);
  ss += __shfl_xor(ss, 32);
  float qs = 0.125f / fmaxf(sqrtf(ss), 1e-12f);
  union { unsigned u[4]; short8 s; } qf0u, qf1u;
#pragma unroll
  for (int r = 0; r < 4; ++r) {
    qf0u.u[r] = pack_bf16(qv[2 * r] * qs, qv[2 * r + 1] * qs);
    qf1u.u[r] = pack_bf16(qv[8 + 2 * r] * qs, qv[8 + 2 * r + 1] * qs);
  }
  short8 qfrag0 = qf0u.s, qfrag1 = qf1u.s;

  const unsigned short* Kg = Kbf + ((size_t)bt * H_ + h) * 512 * 64;
  const unsigned short* Vg = Vbf + ((size_t)bt * H_ + h) * 64 * 512;

  f4 acc[4];
#pragma unroll
  for (int dt = 0; dt < 4; ++dt) acc[dt] = (f4){0.f, 0.f, 0.f, 0.f};
  float mrun = -3.0e38f, lrun = 0.f;
  bool hi_half = (lane >= 32);
  int qh2 = (q & 1) * 2;

  for (int j0 = 0; j0 < 512; j0 += 64) {
    __syncthreads();
#pragma unroll
    for (int p = 0; p < 2; ++p) {
      int cid = tid + p * 256;          // 512 16B-chunks per tile
      int row = cid >> 3, ch = cid & 7;
      int sw = (ch ^ (row & 7)) * 8;
      *(uint4*)&Ka[row * 64 + sw] =
          *(const uint4*)(Kg + (size_t)(j0 + row) * 64 + ch * 8);
      *(uint4*)&Va[row * 64 + sw] =
          *(const uint4*)(Vg + (size_t)row * 512 + j0 + ch * 8);
    }
    __syncthreads();

    // ---- S^T tiles: 4 x (16j x 16i), k over d=64 in 2 steps ----
    f4 sc[4];
#pragma unroll
    for (int jt = 0; jt < 4; ++jt) {
      int row = jt * 16 + l15;
      int swz = row & 7;
      short8 k0 = *(const short8*)&Ka[row * 64 + ((q ^ swz) * 8)];
      short8 k1 = *(const short8*)&Ka[row * 64 + (((4 + q) ^ swz) * 8)];
      f4 c = {0.f, 0.f, 0.f, 0.f};
      c = __builtin_amdgcn_mfma_f32_16x16x32_bf16(k0, qfrag0, c, 0, 0, 0);
      c = __builtin_amdgcn_mfma_f32_16x16x32_bf16(k1, qfrag1, c, 0, 0, 0);
      sc[jt] = c;
    }

    // ---- online softmax over these 64 j (per column i) ----
    float tm = -3.0e38f;
#pragma unroll
    for (int jt = 0; jt < 4; ++jt)
#pragma unroll
      for (int r = 0; r < 4; ++r) tm = fmaxf(tm, sc[jt][r]);
    tm = fmaxf(tm, __shfl_xor(tm, 16));
    tm = fmaxf(tm, __shfl_xor(tm, 32));
    float mn = fmaxf(mrun, tm);
    float alpha = __expf(mrun - mn);
    mrun = mn;
    float ls = 0.f;
#pragma unroll
    for (int jt = 0; jt < 4; ++jt)
#pragma unroll
      for (int r = 0; r < 4; ++r) {
        float p = __expf(sc[jt][r] - mn);
        sc[jt][r] = p;
        ls += p;
      }
    ls += __shfl_xor(ls, 16);
    ls += __shfl_xor(ls, 32);
    lrun = lrun * alpha + ls;
#pragma unroll
    for (int dt = 0; dt < 4; ++dt) acc[dt] = acc[dt] * alpha;

    unsigned pk01[4], pk23[4];
#pragma unroll
    for (int jt = 0; jt < 4; ++jt) {
      pk01[jt] = pack_bf16(sc[jt][0], sc[jt][1]);
      pk23[jt] = pack_bf16(sc[jt][2], sc[jt][3]);
    }

    // ---- PV: O^T(64d x 16i) += V^T . P^T, K=32 per step ----
#pragma unroll
    for (int ks2 = 0; ks2 < 2; ++ks2) {
      union { unsigned u[4]; short8 s; } bu;
#pragma unroll
      for (int r = 0; r < 4; ++r) {
        int src = (qh2 + (r >> 1)) * 16 + l15;
        unsigned pl = (r & 1) ? pk23[ks2 * 2] : pk01[ks2 * 2];
        unsigned ph = (r & 1) ? pk23[ks2 * 2 + 1] : pk01[ks2 * 2 + 1];
        unsigned lo = __shfl(pl, src);
        unsigned hi = __shfl(ph, src);
        bu.u[r] = hi_half ? hi : lo;
      }
      short8 bfrag = bu.s;
#pragma unroll
      for (int dt = 0; dt < 4; ++dt) {
        int row = dt * 16 + l15;
        short8 vf =
            *(const short8*)&Va[row * 64 + (((ks2 * 4 + q) ^ (row & 7)) * 8)];
        acc[dt] = __builtin_amdgcn_mfma_f32_16x16x32_bf16(vf, bfrag, acc[dt],
                                                          0, 0, 0);
      }
    }
  }

  // ---- epilogue: /l, *gw, store O^T into oT (c = h*64+d rows) ----
  float g = gw[bt * H_ + h];
  float inv = g / lrun;
  float* ob = oT + ((size_t)bt * 512 + h * 64) * 512 + iglob;
#pragma unroll
  for (int dt = 0; dt < 4; ++dt)
#pragma unroll
    for (int r = 0; r < 4; ++r)
      ob[(size_t)(dt * 16 + q * 4 + r) * 512] = acc[dt][r] * inv;
}

extern "C" void kernel_launch(void* const* d_in, const int* in_sizes, int n_in,
                              void* d_out, int out_size, void* d_ws, size_t ws_size,
                              hipStream_t stream) {
  const float* e   = (const float*)d_in[0];
  const float* x   = (const float*)d_in[1];
  const float* Wq  = (const float*)d_in[2];
  const float* bq  = (const float*)d_in[3];
  const float* Wkv = (const float*)d_in[4];
  const float* bkv = (const float*)d_in[5];
  const float* Wm  = (const float*)d_in[6];
  const float* bm  = (const float*)d_in[7];
  const float* Wg1 = (const float*)d_in[8];
  const float* bg1 = (const float*)d_in[9];
  const float* Wg2 = (const float*)d_in[10];
  const float* bg2 = (const float*)d_in[11];
  float* out = (float*)d_out;

  float* ws = (float*)d_ws;
  float* pooled = ws;                          // 16384
  float* gwp    = ws + 16384;                  // 256
  float* qT     = ws + 16640;                  // 8388608 floats
  float* kvT    = qT + 8388608;                // 16777216 floats
  float* oT     = kvT;                         // alias: kvT dead when attn writes
  unsigned short* Kbf = (unsigned short*)(kvT + 16777216);  // 8388608 bf16
  unsigned short* Vbf = Kbf + 8388608;                      // 8388608 bf16

  const long CTL = (long)C_ * T_ * L_;
  const long TCL = (long)T_ * C_ * L_;
  const long CL  = (long)C_ * L_;
  const long TL  = (long)T_ * L_;

  pool_kernel<<<dim3(B_ * C_ * T_ / 4), dim3(256), 0, stream>>>(e, pooled);
  gate_kernel<<<dim3(B_ * T_), dim3(256), 0, stream>>>(pooled, Wg1, bg1, Wg2,
                                                       bg2, gwp);
  // q^T = Wq @ e^T  (raw; normalization happens inside attn)
  gemm512_kernel<<<dim3(8, 8, B_ * T_), dim3(256), 0, stream>>>(
      Wq, bq, e, CTL, (long)L_, TL, qT, TCL, CL, (long)L_, nullptr);
  // kv^T = Wkv @ x^T
  gemm512_kernel<<<dim3(8, 16, B_ * T_), dim3(256), 0, stream>>>(
      Wkv, bkv, x, CTL, (long)L_, TL, kvT, 2 * TCL, 2 * CL, (long)L_, nullptr);
  // normalize k, v(*gw) -> bf16 frag-friendly buffers
  norm_kernel<<<dim3(2, 2 * H_, B_ * T_), dim3(256), 0, stream>>>(kvT, gwp, Kbf,
                                                                  Vbf);
  // MFMA flash attention -> oT (in dead kvT region)
  attn_kernel<<<dim3(8, H_, B_ * T_), dim3(256), 0, stream>>>(qT, Kbf, Vbf, gwp,
                                                              oT);
  // out = Wm @ oT + bm + x
  gemm512_kernel<<<dim3(8, 8, B_ * T_), dim3(256), 0, stream>>>(
      Wm, bm, oT, TCL, CL, (long)L_, out, CTL, (long)L_, TL, x);
}

// Round 3
// 274.662 us; speedup vs baseline: 5.2377x; 2.5804x over previous
//
#include <hip/hip_runtime.h>
#include <math.h>

#define B_ 4
#define C_ 512
#define T_ 8
#define L_ 512
#define H_ 8
#define HD_ 64

typedef unsigned short ushort_t;
using short8 = __attribute__((ext_vector_type(8))) short;
using f4 = __attribute__((ext_vector_type(4))) float;

#define GLOAD_LDS(gp, lp)                                                      \
  __builtin_amdgcn_global_load_lds(                                            \
      (const __attribute__((address_space(1))) unsigned int*)(gp),             \
      (__attribute__((address_space(3))) unsigned int*)(lp), 16, 0, 0)

// RNE float->bf16 pack (a -> low 16, b -> high 16). Finite inputs only.
__device__ __forceinline__ unsigned pack_bf16(float a, float b) {
  union { float f; unsigned u; } ua, ub;
  ua.f = a; ub.f = b;
  unsigned ra = (ua.u + 0x7FFFu + ((ua.u >> 16) & 1u)) >> 16;
  unsigned rb = (ub.u + 0x7FFFu + ((ub.u >> 16) & 1u)) >> 16;
  return (rb << 16) | (ra & 0xFFFFu);
}
__device__ __forceinline__ ushort_t bf16_1(float a) {
  union { float f; unsigned u; } ua; ua.f = a;
  return (ushort_t)((ua.u + 0x7FFFu + ((ua.u >> 16) & 1u)) >> 16);
}

// ---------------------------------------------------------------------------
// Workspace (floats), ~102.9 MB total:
//   pooled 16384 | gwp 256 | h1 16384 | then bf16 buffers (counted in floats):
//   ebfT,xbfT,Qbf,Kbf,Vbf,obfT: 6 x 4,194,304 | Wqb 131072 | Wkvb 262144 | Wmb 131072
// Layouts: ebfT/xbfT/obfT = [bt][l][c] bf16 (K-contiguous for GEMM B^T operand)
//          Qbf/Kbf = [bt][h][l][d] bf16 (pre-normalized; Q also *0.125)
//          Vbf     = [bt][h][d][l] bf16 (normalized * gw)
// ---------------------------------------------------------------------------

__global__ __launch_bounds__(256) void pool_kernel(const float* __restrict__ e,
                                                   float* __restrict__ pooled) {
  int wave = threadIdx.x >> 6;
  int lane = threadIdx.x & 63;
  int r = blockIdx.x * 4 + wave;  // r = (b*C + c)*T + t
  int t = r % T_;
  int c = (r / T_) % C_;
  int b = r / (T_ * C_);
  const float* row = e + (size_t)r * L_;
  float s = 0.f;
#pragma unroll
  for (int i = 0; i < L_ / 64; ++i) s += row[lane + i * 64];
#pragma unroll
  for (int off = 32; off > 0; off >>= 1) s += __shfl_down(s, off, 64);
  if (lane == 0) pooled[(b * T_ + t) * C_ + c] = s * (1.0f / L_);
}

// h1[bt][row] = tanh(dot(Wg1[row], pooled[bt]) + bg1[row]); one wave per row.
__global__ __launch_bounds__(256) void gate1_kernel(const float* __restrict__ pooled,
                                                    const float* __restrict__ Wg1,
                                                    const float* __restrict__ bg1,
                                                    float* __restrict__ h1) {
  int w = threadIdx.x >> 6, lane = threadIdx.x & 63;
  int row = blockIdx.x * 4 + w;
  int bt = blockIdx.y;
  const float* wr = Wg1 + (size_t)row * C_;
  const float* pr = pooled + bt * C_;
  float s = 0.f;
#pragma unroll
  for (int i = 0; i < 8; ++i) s += wr[lane + i * 64] * pr[lane + i * 64];
#pragma unroll
  for (int off = 32; off > 0; off >>= 1) s += __shfl_down(s, off, 64);
  if (lane == 0) h1[bt * C_ + row] = tanhf(s + bg1[row]);
}

__global__ __launch_bounds__(256) void gate2_kernel(const float* __restrict__ h1,
                                                    const float* __restrict__ Wg2,
                                                    const float* __restrict__ bg2,
                                                    float* __restrict__ gwp) {
  __shared__ float part[256];
  __shared__ float gl[H_];
  int bt = blockIdx.x, tid = threadIdx.x;
  int h = tid >> 5, s = tid & 31;
  const float* w2 = Wg2 + (size_t)h * C_;
  const float* hb = h1 + bt * C_;
  float p = 0.f;
  for (int c = s; c < C_; c += 32) p += w2[c] * hb[c];
  part[tid] = p;
  __syncthreads();
  if (tid < H_) {
    float a = bg2[tid];
    for (int i = 0; i < 32; ++i) a += part[tid * 32 + i];
    gl[tid] = a;
  }
  __syncthreads();
  if (tid == 0) {
    float m = -1e30f;
    for (int i = 0; i < H_; ++i) m = fmaxf(m, gl[i]);
    float sum = 0.f;
    float ex[H_];
    for (int i = 0; i < H_; ++i) { ex[i] = expf(gl[i] - m); sum += ex[i]; }
    for (int i = 0; i < H_; ++i) gwp[bt * H_ + i] = ex[i] / sum;
  }
}

// fp32 -> bf16 elementwise (weights). n multiple of 8.
__global__ __launch_bounds__(256) void cvt_kernel(const float* __restrict__ s,
                                                  ushort_t* __restrict__ d) {
  int i = (blockIdx.x * 256 + threadIdx.x) * 8;
  float4 a = *(const float4*)(s + i);
  float4 b = *(const float4*)(s + i + 4);
  uint4 o;
  o.x = pack_bf16(a.x, a.y); o.y = pack_bf16(a.z, a.w);
  o.z = pack_bf16(b.x, b.y); o.w = pack_bf16(b.z, b.w);
  *(uint4*)(d + i) = o;
}

// Transpose-convert: src (B,C,T,L) fp32 -> dst[bt][l][c] bf16. 64x64 tiles.
__global__ __launch_bounds__(256) void tconv_kernel(const float* __restrict__ src,
                                                    ushort_t* __restrict__ dst) {
  __shared__ float tb[64][65];
  int tid = threadIdx.x;
  int b = blockIdx.z >> 3, t = blockIdx.z & 7;
  int c0 = blockIdx.y * 64, l0 = blockIdx.x * 64;
  const float* sp = src + (((size_t)(b * C_ + c0) * T_) + t) * L_ + l0;
  int j = tid & 63, i0 = tid >> 6;
#pragma unroll
  for (int p = 0; p < 16; ++p) {
    int i = p * 4 + i0;
    tb[i][j] = sp[(size_t)i * (T_ * L_) + j];
  }
  __syncthreads();
  int ii = (tid & 31) * 2, jj0 = tid >> 5;
  ushort_t* dp = dst + ((size_t)blockIdx.z * L_ + l0) * C_ + c0;
#pragma unroll
  for (int p = 0; p < 8; ++p) {
    int jj = p * 8 + jj0;
    *(unsigned*)(dp + (size_t)jj * C_ + ii) = pack_bf16(tb[ii][jj], tb[ii + 1][jj]);
  }
}

// ---------------------------------------------------------------------------
// bf16 MFMA GEMM: C[m][n] = A[m][k] . BT[n][k], K=512, 128x128 tile, BK=32.
// A row-major (shared over bt), BT per-bt [n][k].
// mode 0: Out fp32 (B,C,T,L) = C + bias[m] + resid    (final projection)
// mode 1: q: per-head-col normalize, * qscale(0.125), write Kdst=[bt][h][l][d]
// mode 2: kv: m<512 -> K like mode1 (scale 1); m>=512 -> V: *gw, Vdst=[bt][h][d][l]
// ---------------------------------------------------------------------------
__global__ __launch_bounds__(256, 2) void gemm_mfma(
    const ushort_t* __restrict__ A, const ushort_t* __restrict__ BT,
    const float* __restrict__ bias, int mode,
    float* __restrict__ Out, const float* __restrict__ resid,
    ushort_t* __restrict__ Kdst, ushort_t* __restrict__ Vdst,
    const float* __restrict__ gwp, float qscale) {
  __shared__ alignas(16) ushort_t As[128 * 32];
  __shared__ alignas(16) ushort_t Bs[128 * 32];
  int tid = threadIdx.x;
  int w = tid >> 6, lane = tid & 63, l15 = lane & 15, q = lane >> 4;
  int n0 = blockIdx.x * 128, m0 = blockIdx.y * 128, bt = blockIdx.z;
  int wm = (w >> 1) * 64, wn = (w & 1) * 64;
  const ushort_t* Bbt = BT + (size_t)bt * C_ * C_;

  int c0 = w * 64 + lane, c1 = 256 + w * 64 + lane;
  const ushort_t* ag0 = A + (size_t)(m0 + (c0 >> 2)) * 512 + (c0 & 3) * 8;
  const ushort_t* ag1 = A + (size_t)(m0 + (c1 >> 2)) * 512 + (c1 & 3) * 8;
  const ushort_t* bg0 = Bbt + (size_t)(n0 + (c0 >> 2)) * 512 + (c0 & 3) * 8;
  const ushort_t* bg1 = Bbt + (size_t)(n0 + (c1 >> 2)) * 512 + (c1 & 3) * 8;
  ushort_t* la0 = As + (size_t)(w * 64) * 8;
  ushort_t* la1 = As + (size_t)(256 + w * 64) * 8;
  ushort_t* lb0 = Bs + (size_t)(w * 64) * 8;
  ushort_t* lb1 = Bs + (size_t)(256 + w * 64) * 8;

  f4 acc[4][4];
#pragma unroll
  for (int i = 0; i < 4; ++i)
#pragma unroll
    for (int j = 0; j < 4; ++j) acc[i][j] = (f4){0.f, 0.f, 0.f, 0.f};

  for (int k0 = 0; k0 < 512; k0 += 32) {
    __syncthreads();
    GLOAD_LDS(ag0 + k0, la0);
    GLOAD_LDS(ag1 + k0, la1);
    GLOAD_LDS(bg0 + k0, lb0);
    GLOAD_LDS(bg1 + k0, lb1);
    __syncthreads();
    short8 af[4], bf[4];
#pragma unroll
    for (int mt = 0; mt < 4; ++mt)
      af[mt] = *(const short8*)&As[(size_t)(wm + mt * 16 + l15) * 32 + q * 8];
#pragma unroll
    for (int nt = 0; nt < 4; ++nt)
      bf[nt] = *(const short8*)&Bs[(size_t)(wn + nt * 16 + l15) * 32 + q * 8];
#pragma unroll
    for (int mt = 0; mt < 4; ++mt)
#pragma unroll
      for (int nt = 0; nt < 4; ++nt)
        acc[mt][nt] =
            __builtin_amdgcn_mfma_f32_16x16x32_bf16(af[mt], bf[nt], acc[mt][nt], 0, 0, 0);
  }

  // ---- epilogue: bias first (rows m = m0+wm+mt*16+q*4+r) ----
#pragma unroll
  for (int mt = 0; mt < 4; ++mt)
#pragma unroll
    for (int r = 0; r < 4; ++r) {
      float bb = bias[m0 + wm + mt * 16 + q * 4 + r];
#pragma unroll
      for (int nt = 0; nt < 4; ++nt) acc[mt][nt][r] += bb;
    }

  if (mode == 0) {
    int b = bt >> 3, t = bt & 7;
    float* Ob = Out + (size_t)b * (C_ * T_ * L_) + (size_t)t * L_;
    const float* Rb = resid + (size_t)b * (C_ * T_ * L_) + (size_t)t * L_;
#pragma unroll
    for (int mt = 0; mt < 4; ++mt)
#pragma unroll
      for (int r = 0; r < 4; ++r) {
        size_t ro = (size_t)(m0 + wm + mt * 16 + q * 4 + r) * (T_ * L_);
#pragma unroll
        for (int nt = 0; nt < 4; ++nt) {
          int n = n0 + wn + nt * 16 + l15;
          Ob[ro + n] = acc[mt][nt][r] + Rb[ro + n];
        }
      }
    return;
  }

  // normalization over the wave's 64 m-rows (= one full head) per column
  float scale[4];
#pragma unroll
  for (int nt = 0; nt < 4; ++nt) {
    float s = 0.f;
#pragma unroll
    for (int mt = 0; mt < 4; ++mt)
#pragma unroll
      for (int r = 0; r < 4; ++r) s += acc[mt][nt][r] * acc[mt][nt][r];
    s += __shfl_xor(s, 16);
    s += __shfl_xor(s, 32);
    scale[nt] = s;
  }
  int hh = ((m0 + wm) >> 6) & 7;
  bool isv = (mode == 2) && (m0 + wm >= 512);
  float mult = isv ? gwp[bt * H_ + hh] : qscale;
#pragma unroll
  for (int nt = 0; nt < 4; ++nt)
    scale[nt] = mult / fmaxf(sqrtf(scale[nt]), 1e-12f);

  if (!isv) {
    ushort_t* Kb = Kdst + (size_t)(bt * H_ + hh) * 512 * 64;
#pragma unroll
    for (int nt = 0; nt < 4; ++nt) {
      int l = n0 + wn + nt * 16 + l15;
      ushort_t* rowp = Kb + (size_t)l * 64;
#pragma unroll
      for (int mt = 0; mt < 4; ++mt) {
        uint2 pk;
        pk.x = pack_bf16(acc[mt][nt][0] * scale[nt], acc[mt][nt][1] * scale[nt]);
        pk.y = pack_bf16(acc[mt][nt][2] * scale[nt], acc[mt][nt][3] * scale[nt]);
        *(uint2*)&rowp[mt * 16 + q * 4] = pk;
      }
    }
  } else {
    ushort_t* Vb = Vdst + (size_t)(bt * H_ + hh) * 64 * 512;
#pragma unroll
    for (int mt = 0; mt < 4; ++mt)
#pragma unroll
      for (int r = 0; r < 4; ++r) {
        int d = mt * 16 + q * 4 + r;
        ushort_t* rp = Vb + (size_t)d * 512 + n0 + wn;
#pragma unroll
        for (int nt = 0; nt < 4; ++nt)
          rp[nt * 16 + l15] = bf16_1(acc[mt][nt][r] * scale[nt]);
      }
  }
}

// Flash MFMA attention; Q pre-normalized (incl 0.125) in Qbf[bt][h][l][d].
// K/V staged via global_load_lds with XOR swizzle on the global side.
// Output: obfT[bt][l][c] bf16 (feeds final GEMM's BT operand).
__global__ __launch_bounds__(256) void attn_kernel(
    const ushort_t* __restrict__ Qbf, const ushort_t* __restrict__ Kbf,
    const ushort_t* __restrict__ Vbf, const float* __restrict__ gwp,
    ushort_t* __restrict__ obfT) {
  __shared__ alignas(16) ushort_t Ka[64 * 64];
  __shared__ alignas(16) ushort_t Va[64 * 64];

  int tid = threadIdx.x;
  int w = tid >> 6, lane = tid & 63, l15 = lane & 15, q = lane >> 4;
  int i0 = blockIdx.x * 64, h = blockIdx.y, bt = blockIdx.z;
  int iglob = i0 + w * 16 + l15;

  const ushort_t* qrow = Qbf + ((size_t)(bt * H_ + h) * 512 + iglob) * 64;
  short8 qfrag0 = *(const short8*)&qrow[q * 8];
  short8 qfrag1 = *(const short8*)&qrow[32 + q * 8];

  const ushort_t* Kg = Kbf + (size_t)(bt * H_ + h) * 512 * 64;
  const ushort_t* Vg = Vbf + (size_t)(bt * H_ + h) * 64 * 512;

  // staging: 512 chunks per tile; LDS slot s of row r holds global chunk s^(r&7)
  int cA = w * 64 + lane, cB = 256 + w * 64 + lane;
  const ushort_t* kg0 = Kg + (size_t)(cA >> 3) * 64 + ((cA & 7) ^ ((cA >> 3) & 7)) * 8;
  const ushort_t* kg1 = Kg + (size_t)(cB >> 3) * 64 + ((cB & 7) ^ ((cB >> 3) & 7)) * 8;
  const ushort_t* vg0 = Vg + (size_t)(cA >> 3) * 512 + ((cA & 7) ^ ((cA >> 3) & 7)) * 8;
  const ushort_t* vg1 = Vg + (size_t)(cB >> 3) * 512 + ((cB & 7) ^ ((cB >> 3) & 7)) * 8;
  ushort_t* lk0 = Ka + (size_t)(w * 64) * 8;
  ushort_t* lk1 = Ka + (size_t)(256 + w * 64) * 8;
  ushort_t* lv0 = Va + (size_t)(w * 64) * 8;
  ushort_t* lv1 = Va + (size_t)(256 + w * 64) * 8;

  f4 acc[4];
#pragma unroll
  for (int dt = 0; dt < 4; ++dt) acc[dt] = (f4){0.f, 0.f, 0.f, 0.f};
  float mrun = -3.0e38f, lrun = 0.f;
  bool hi_half = (lane >= 32);
  int qh2 = (q & 1) * 2;

  for (int j0 = 0; j0 < 512; j0 += 64) {
    __syncthreads();
    GLOAD_LDS(kg0 + (size_t)j0 * 64, lk0);
    GLOAD_LDS(kg1 + (size_t)j0 * 64, lk1);
    GLOAD_LDS(vg0 + j0, lv0);
    GLOAD_LDS(vg1 + j0, lv1);
    __syncthreads();

    // ---- S^T tiles: 4 x (16j x 16i) ----
    f4 sc[4];
#pragma unroll
    for (int jt = 0; jt < 4; ++jt) {
      int row = jt * 16 + l15;
      int swz = row & 7;
      short8 k0 = *(const short8*)&Ka[row * 64 + ((q ^ swz) * 8)];
      short8 k1 = *(const short8*)&Ka[row * 64 + (((4 + q) ^ swz) * 8)];
      f4 c = {0.f, 0.f, 0.f, 0.f};
      c = __builtin_amdgcn_mfma_f32_16x16x32_bf16(k0, qfrag0, c, 0, 0, 0);
      c = __builtin_amdgcn_mfma_f32_16x16x32_bf16(k1, qfrag1, c, 0, 0, 0);
      sc[jt] = c;
    }

    // ---- online softmax ----
    float tm = -3.0e38f;
#pragma unroll
    for (int jt = 0; jt < 4; ++jt)
#pragma unroll
      for (int r = 0; r < 4; ++r) tm = fmaxf(tm, sc[jt][r]);
    tm = fmaxf(tm, __shfl_xor(tm, 16));
    tm = fmaxf(tm, __shfl_xor(tm, 32));
    float mn = fmaxf(mrun, tm);
    float alpha = __expf(mrun - mn);
    mrun = mn;
    float ls = 0.f;
#pragma unroll
    for (int jt = 0; jt < 4; ++jt)
#pragma unroll
      for (int r = 0; r < 4; ++r) {
        float p = __expf(sc[jt][r] - mn);
        sc[jt][r] = p;
        ls += p;
      }
    ls += __shfl_xor(ls, 16);
    ls += __shfl_xor(ls, 32);
    lrun = lrun * alpha + ls;
#pragma unroll
    for (int dt = 0; dt < 4; ++dt) acc[dt] = acc[dt] * alpha;

    unsigned pk01[4], pk23[4];
#pragma unroll
    for (int jt = 0; jt < 4; ++jt) {
      pk01[jt] = pack_bf16(sc[jt][0], sc[jt][1]);
      pk23[jt] = pack_bf16(sc[jt][2], sc[jt][3]);
    }

    // ---- PV: O^T += V^T . P^T ----
#pragma unroll
    for (int ks2 = 0; ks2 < 2; ++ks2) {
      union { unsigned u[4]; short8 s; } bu;
#pragma unroll
      for (int r = 0; r < 4; ++r) {
        int src = (qh2 + (r >> 1)) * 16 + l15;
        unsigned pl = (r & 1) ? pk23[ks2 * 2] : pk01[ks2 * 2];
        unsigned ph = (r & 1) ? pk23[ks2 * 2 + 1] : pk01[ks2 * 2 + 1];
        unsigned lo = __shfl(pl, src);
        unsigned hi = __shfl(ph, src);
        bu.u[r] = hi_half ? hi : lo;
      }
      short8 bfrag = bu.s;
#pragma unroll
      for (int dt = 0; dt < 4; ++dt) {
        int row = dt * 16 + l15;
        short8 vf =
            *(const short8*)&Va[row * 64 + (((ks2 * 4 + q) ^ (row & 7)) * 8)];
        acc[dt] = __builtin_amdgcn_mfma_f32_16x16x32_bf16(vf, bfrag, acc[dt], 0, 0, 0);
      }
    }
  }

  // ---- epilogue: *gw/l, store bf16 to obfT[l][c] ----
  float g = gwp[bt * H_ + h];
  float inv = g / lrun;
  ushort_t* ob = obfT + ((size_t)(bt * 512 + iglob)) * 512 + h * 64;
#pragma unroll
  for (int dt = 0; dt < 4; ++dt) {
    uint2 pk;
    pk.x = pack_bf16(acc[dt][0] * inv, acc[dt][1] * inv);
    pk.y = pack_bf16(acc[dt][2] * inv, acc[dt][3] * inv);
    *(uint2*)&ob[dt * 16 + q * 4] = pk;
  }
}

extern "C" void kernel_launch(void* const* d_in, const int* in_sizes, int n_in,
                              void* d_out, int out_size, void* d_ws, size_t ws_size,
                              hipStream_t stream) {
  const float* e   = (const float*)d_in[0];
  const float* x   = (const float*)d_in[1];
  const float* Wq  = (const float*)d_in[2];
  const float* bq  = (const float*)d_in[3];
  const float* Wkv = (const float*)d_in[4];
  const float* bkv = (const float*)d_in[5];
  const float* Wm  = (const float*)d_in[6];
  const float* bm  = (const float*)d_in[7];
  const float* Wg1 = (const float*)d_in[8];
  const float* bg1 = (const float*)d_in[9];
  const float* Wg2 = (const float*)d_in[10];
  const float* bg2 = (const float*)d_in[11];
  float* out = (float*)d_out;

  float* ws = (float*)d_ws;
  float* pooled = ws;                  // 16384
  float* gwp    = ws + 16384;          // 256
  float* h1buf  = ws + 16640;          // 16384
  float* fb     = ws + 33024;
  ushort_t* ebfT = (ushort_t*)(fb);
  ushort_t* xbfT = (ushort_t*)(fb + 1 * 4194304);
  ushort_t* Qbf  = (ushort_t*)(fb + 2 * 4194304);
  ushort_t* Kbf  = (ushort_t*)(fb + 3 * 4194304);
  ushort_t* Vbf  = (ushort_t*)(fb + 4 * 4194304);
  ushort_t* obfT = (ushort_t*)(fb + 5 * 4194304);
  ushort_t* Wqb  = (ushort_t*)(fb + 6 * 4194304);
  ushort_t* Wkvb = Wqb + 262144;
  ushort_t* Wmb  = Wkvb + 524288;

  // weight conversions
  cvt_kernel<<<dim3(128), dim3(256), 0, stream>>>(Wq, Wqb);
  cvt_kernel<<<dim3(256), dim3(256), 0, stream>>>(Wkv, Wkvb);
  cvt_kernel<<<dim3(128), dim3(256), 0, stream>>>(Wm, Wmb);
  // activation transpose-converts
  tconv_kernel<<<dim3(8, 8, 32), dim3(256), 0, stream>>>(e, ebfT);
  tconv_kernel<<<dim3(8, 8, 32), dim3(256), 0, stream>>>(x, xbfT);
  // pooling + gating
  pool_kernel<<<dim3(B_ * C_ * T_ / 4), dim3(256), 0, stream>>>(e, pooled);
  gate1_kernel<<<dim3(128, 32), dim3(256), 0, stream>>>(pooled, Wg1, bg1, h1buf);
  gate2_kernel<<<dim3(32), dim3(256), 0, stream>>>(h1buf, Wg2, bg2, gwp);
  // q projection (normalize + 0.125) -> Qbf
  gemm_mfma<<<dim3(4, 4, 32), dim3(256), 0, stream>>>(
      Wqb, ebfT, bq, 1, nullptr, nullptr, Qbf, nullptr, gwp, 0.125f);
  // kv projection (k: normalize; v: normalize*gw) -> Kbf, Vbf
  gemm_mfma<<<dim3(4, 8, 32), dim3(256), 0, stream>>>(
      Wkvb, xbfT, bkv, 2, nullptr, nullptr, Kbf, Vbf, gwp, 1.0f);
  // attention -> obfT
  attn_kernel<<<dim3(8, H_, 32), dim3(256), 0, stream>>>(Qbf, Kbf, Vbf, gwp, obfT);
  // output projection + bias + residual -> out
  gemm_mfma<<<dim3(4, 4, 32), dim3(256), 0, stream>>>(
      Wmb, obfT, bm, 0, out, x, nullptr, nullptr, gwp, 1.0f);
}

// Round 4
// 260.288 us; speedup vs baseline: 5.5270x; 1.0552x over previous
//
#include <hip/hip_runtime.h>
#include <math.h>

#define B_ 4
#define C_ 512
#define T_ 8
#define L_ 512
#define H_ 8
#define HD_ 64

typedef unsigned short ushort_t;
using short8 = __attribute__((ext_vector_type(8))) short;
using f4 = __attribute__((ext_vector_type(4))) float;

#define GLOAD_LDS(gp, lp)                                                      \
  __builtin_amdgcn_global_load_lds(                                            \
      (const __attribute__((address_space(1))) unsigned int*)(gp),             \
      (__attribute__((address_space(3))) unsigned int*)(lp), 16, 0, 0)

// RNE float->bf16 pack (a -> low 16, b -> high 16). Finite inputs only.
__device__ __forceinline__ unsigned pack_bf16(float a, float b) {
  union { float f; unsigned u; } ua, ub;
  ua.f = a; ub.f = b;
  unsigned ra = (ua.u + 0x7FFFu + ((ua.u >> 16) & 1u)) >> 16;
  unsigned rb = (ub.u + 0x7FFFu + ((ub.u >> 16) & 1u)) >> 16;
  return (rb << 16) | (ra & 0xFFFFu);
}
__device__ __forceinline__ ushort_t bf16_1(float a) {
  union { float f; unsigned u; } ua; ua.f = a;
  return (ushort_t)((ua.u + 0x7FFFu + ((ua.u >> 16) & 1u)) >> 16);
}

// ---------------------------------------------------------------------------
// Workspace: pooled 16384 | gwp 256 | h1 16384 | bf16 buffers:
//   ebfT,xbfT,Qbf,Kbf,Vbf,obfT 6x4194304 fl | Wqb 131072 | Wkvb 262144 | Wmb 131072
// Layouts: ebfT/xbfT/obfT = [bt][l][c] bf16 ; Qbf/Kbf = [bt][h][l][d]
//          (pre-normalized; Q also *0.125) ; Vbf = [bt][h][d][l] (*gw)
// ---------------------------------------------------------------------------

// h1[bt][row] = tanh(dot(Wg1[row], pooled[bt]) + bg1[row]); one wave per row.
__global__ __launch_bounds__(256) void gate1_kernel(const float* __restrict__ pooled,
                                                    const float* __restrict__ Wg1,
                                                    const float* __restrict__ bg1,
                                                    float* __restrict__ h1) {
  int w = threadIdx.x >> 6, lane = threadIdx.x & 63;
  int row = blockIdx.x * 4 + w;
  int bt = blockIdx.y;
  const float* wr = Wg1 + (size_t)row * C_;
  const float* pr = pooled + bt * C_;
  float s = 0.f;
#pragma unroll
  for (int i = 0; i < 8; ++i) s += wr[lane + i * 64] * pr[lane + i * 64];
#pragma unroll
  for (int off = 32; off > 0; off >>= 1) s += __shfl_down(s, off, 64);
  if (lane == 0) h1[bt * C_ + row] = tanhf(s + bg1[row]);
}

__global__ __launch_bounds__(256) void gate2_kernel(const float* __restrict__ h1,
                                                    const float* __restrict__ Wg2,
                                                    const float* __restrict__ bg2,
                                                    float* __restrict__ gwp) {
  __shared__ float part[256];
  __shared__ float gl[H_];
  int bt = blockIdx.x, tid = threadIdx.x;
  int h = tid >> 5, s = tid & 31;
  const float* w2 = Wg2 + (size_t)h * C_;
  const float* hb = h1 + bt * C_;
  float p = 0.f;
  for (int c = s; c < C_; c += 32) p += w2[c] * hb[c];
  part[tid] = p;
  __syncthreads();
  if (tid < H_) {
    float a = bg2[tid];
    for (int i = 0; i < 32; ++i) a += part[tid * 32 + i];
    gl[tid] = a;
  }
  __syncthreads();
  if (tid == 0) {
    float m = -1e30f;
    for (int i = 0; i < H_; ++i) m = fmaxf(m, gl[i]);
    float sum = 0.f;
    float ex[H_];
    for (int i = 0; i < H_; ++i) { ex[i] = expf(gl[i] - m); sum += ex[i]; }
    for (int i = 0; i < H_; ++i) gwp[bt * H_ + i] = ex[i] / sum;
  }
}

// fp32 -> bf16 elementwise (weights). n multiple of 8.
__global__ __launch_bounds__(256) void cvt_kernel(const float* __restrict__ s,
                                                  ushort_t* __restrict__ d) {
  int i = (blockIdx.x * 256 + threadIdx.x) * 8;
  float4 a = *(const float4*)(s + i);
  float4 b = *(const float4*)(s + i + 4);
  uint4 o;
  o.x = pack_bf16(a.x, a.y); o.y = pack_bf16(a.z, a.w);
  o.z = pack_bf16(b.x, b.y); o.w = pack_bf16(b.z, b.w);
  *(uint4*)(d + i) = o;
}

// Transpose-convert: src (B,C,T,L) fp32 -> dst[bt][l][c] bf16. 64x64 tiles.
// If pooled != nullptr, also atomically accumulate mean over l into pooled.
__global__ __launch_bounds__(256) void tconv_kernel(const float* __restrict__ src,
                                                    ushort_t* __restrict__ dst,
                                                    float* __restrict__ pooled) {
  __shared__ float tb[64][65];
  int tid = threadIdx.x;
  int b = blockIdx.z >> 3, t = blockIdx.z & 7;
  int c0 = blockIdx.y * 64, l0 = blockIdx.x * 64;
  const float* sp = src + (((size_t)(b * C_ + c0) * T_) + t) * L_ + l0;
  int j = tid & 63, i0 = tid >> 6;
#pragma unroll
  for (int p = 0; p < 16; ++p) {
    int i = p * 4 + i0;
    tb[i][j] = sp[(size_t)i * (T_ * L_) + j];
  }
  __syncthreads();
  if (pooled) {
    int c = tid >> 2, part = tid & 3;
    float s = 0.f;
#pragma unroll
    for (int k = 0; k < 16; ++k) s += tb[c][part * 16 + k];
    s += __shfl_down(s, 1);
    s += __shfl_down(s, 2);
    if (part == 0) atomicAdd(&pooled[blockIdx.z * C_ + c0 + c], s * (1.0f / L_));
  }
  int ii = (tid & 31) * 2, jj0 = tid >> 5;
  ushort_t* dp = dst + ((size_t)blockIdx.z * L_ + l0) * C_ + c0;
#pragma unroll
  for (int p = 0; p < 8; ++p) {
    int jj = p * 8 + jj0;
    *(unsigned*)(dp + (size_t)jj * C_ + ii) = pack_bf16(tb[ii][jj], tb[ii + 1][jj]);
  }
}

// ---------------------------------------------------------------------------
// bf16 MFMA GEMM: C[m][n] = A[m][k] . BT[n][k], K=512, 128x128 tile, BK=32.
// mode 0: Out fp32 (B,C,T,L) = C + bias[m] + resid
// mode 1: q: per-head-col normalize, * qscale(0.125), write Kdst=[bt][h][l][d]
// mode 2: kv: m<512 -> K like mode1 (scale 1); m>=512 -> V: *gw, Vdst=[bt][h][d][l]
// ---------------------------------------------------------------------------
__global__ __launch_bounds__(256, 2) void gemm_mfma(
    const ushort_t* __restrict__ A, const ushort_t* __restrict__ BT,
    const float* __restrict__ bias, int mode,
    float* __restrict__ Out, const float* __restrict__ resid,
    ushort_t* __restrict__ Kdst, ushort_t* __restrict__ Vdst,
    const float* __restrict__ gwp, float qscale) {
  __shared__ alignas(16) ushort_t As[128 * 32];
  __shared__ alignas(16) ushort_t Bs[128 * 32];
  int tid = threadIdx.x;
  int w = tid >> 6, lane = tid & 63, l15 = lane & 15, q = lane >> 4;
  int n0 = blockIdx.x * 128, m0 = blockIdx.y * 128, bt = blockIdx.z;
  int wm = (w >> 1) * 64, wn = (w & 1) * 64;
  const ushort_t* Bbt = BT + (size_t)bt * C_ * C_;

  int c0 = w * 64 + lane, c1 = 256 + w * 64 + lane;
  const ushort_t* ag0 = A + (size_t)(m0 + (c0 >> 2)) * 512 + (c0 & 3) * 8;
  const ushort_t* ag1 = A + (size_t)(m0 + (c1 >> 2)) * 512 + (c1 & 3) * 8;
  const ushort_t* bg0 = Bbt + (size_t)(n0 + (c0 >> 2)) * 512 + (c0 & 3) * 8;
  const ushort_t* bg1 = Bbt + (size_t)(n0 + (c1 >> 2)) * 512 + (c1 & 3) * 8;
  ushort_t* la0 = As + (size_t)(w * 64) * 8;
  ushort_t* la1 = As + (size_t)(256 + w * 64) * 8;
  ushort_t* lb0 = Bs + (size_t)(w * 64) * 8;
  ushort_t* lb1 = Bs + (size_t)(256 + w * 64) * 8;

  f4 acc[4][4];
#pragma unroll
  for (int i = 0; i < 4; ++i)
#pragma unroll
    for (int j = 0; j < 4; ++j) acc[i][j] = (f4){0.f, 0.f, 0.f, 0.f};

  for (int k0 = 0; k0 < 512; k0 += 32) {
    __syncthreads();
    GLOAD_LDS(ag0 + k0, la0);
    GLOAD_LDS(ag1 + k0, la1);
    GLOAD_LDS(bg0 + k0, lb0);
    GLOAD_LDS(bg1 + k0, lb1);
    __syncthreads();
    short8 af[4], bf[4];
#pragma unroll
    for (int mt = 0; mt < 4; ++mt)
      af[mt] = *(const short8*)&As[(size_t)(wm + mt * 16 + l15) * 32 + q * 8];
#pragma unroll
    for (int nt = 0; nt < 4; ++nt)
      bf[nt] = *(const short8*)&Bs[(size_t)(wn + nt * 16 + l15) * 32 + q * 8];
#pragma unroll
    for (int mt = 0; mt < 4; ++mt)
#pragma unroll
      for (int nt = 0; nt < 4; ++nt)
        acc[mt][nt] =
            __builtin_amdgcn_mfma_f32_16x16x32_bf16(af[mt], bf[nt], acc[mt][nt], 0, 0, 0);
  }

#pragma unroll
  for (int mt = 0; mt < 4; ++mt)
#pragma unroll
    for (int r = 0; r < 4; ++r) {
      float bb = bias[m0 + wm + mt * 16 + q * 4 + r];
#pragma unroll
      for (int nt = 0; nt < 4; ++nt) acc[mt][nt][r] += bb;
    }

  if (mode == 0) {
    int b = bt >> 3, t = bt & 7;
    float* Ob = Out + (size_t)b * (C_ * T_ * L_) + (size_t)t * L_;
    const float* Rb = resid + (size_t)b * (C_ * T_ * L_) + (size_t)t * L_;
#pragma unroll
    for (int mt = 0; mt < 4; ++mt)
#pragma unroll
      for (int r = 0; r < 4; ++r) {
        size_t ro = (size_t)(m0 + wm + mt * 16 + q * 4 + r) * (T_ * L_);
#pragma unroll
        for (int nt = 0; nt < 4; ++nt) {
          int n = n0 + wn + nt * 16 + l15;
          Ob[ro + n] = acc[mt][nt][r] + Rb[ro + n];
        }
      }
    return;
  }

  // normalization over the wave's 64 m-rows (= one full head) per column
  float scale[4];
#pragma unroll
  for (int nt = 0; nt < 4; ++nt) {
    float s = 0.f;
#pragma unroll
    for (int mt = 0; mt < 4; ++mt)
#pragma unroll
      for (int r = 0; r < 4; ++r) s += acc[mt][nt][r] * acc[mt][nt][r];
    s += __shfl_xor(s, 16);
    s += __shfl_xor(s, 32);
    scale[nt] = s;
  }
  int hh = ((m0 + wm) >> 6) & 7;
  bool isv = (mode == 2) && (m0 + wm >= 512);
  float mult = isv ? gwp[bt * H_ + hh] : qscale;
#pragma unroll
  for (int nt = 0; nt < 4; ++nt)
    scale[nt] = mult / fmaxf(sqrtf(scale[nt]), 1e-12f);

  if (!isv) {
    ushort_t* Kb = Kdst + (size_t)(bt * H_ + hh) * 512 * 64;
#pragma unroll
    for (int nt = 0; nt < 4; ++nt) {
      int l = n0 + wn + nt * 16 + l15;
      ushort_t* rowp = Kb + (size_t)l * 64;
#pragma unroll
      for (int mt = 0; mt < 4; ++mt) {
        uint2 pk;
        pk.x = pack_bf16(acc[mt][nt][0] * scale[nt], acc[mt][nt][1] * scale[nt]);
        pk.y = pack_bf16(acc[mt][nt][2] * scale[nt], acc[mt][nt][3] * scale[nt]);
        *(uint2*)&rowp[mt * 16 + q * 4] = pk;
      }
    }
  } else {
    ushort_t* Vb = Vdst + (size_t)(bt * H_ + hh) * 64 * 512;
#pragma unroll
    for (int mt = 0; mt < 4; ++mt)
#pragma unroll
      for (int r = 0; r < 4; ++r) {
        int d = mt * 16 + q * 4 + r;
        ushort_t* rp = Vb + (size_t)d * 512 + n0 + wn;
#pragma unroll
        for (int nt = 0; nt < 4; ++nt)
          rp[nt * 16 + l15] = bf16_1(acc[mt][nt][r] * scale[nt]);
      }
  }
}

// Flash MFMA attention, one block per (h,bt): 512 threads = 8 waves, 64 queries
// per wave (4 x 16-i frags). No LDS, no barriers: K/V fragments loaded straight
// to registers (4-wave redundancy served by L1). No-max softmax: |s|<=0.13 so
// exp cannot overflow; softmax shift-invariance makes this exact. Per-lane
// partial l-sums, reduced once in the epilogue.
__global__ __launch_bounds__(512, 2) void attn_kernel(
    const ushort_t* __restrict__ Qbf, const ushort_t* __restrict__ Kbf,
    const ushort_t* __restrict__ Vbf, const float* __restrict__ gwp,
    ushort_t* __restrict__ obfT) {
  int tid = threadIdx.x;
  int w = tid >> 6, lane = tid & 63, l15 = lane & 15, q = lane >> 4;
  int h = blockIdx.x, bt = blockIdx.y;

  const ushort_t* Qg = Qbf + (size_t)(bt * H_ + h) * 512 * 64;
  const ushort_t* Kg = Kbf + (size_t)(bt * H_ + h) * 512 * 64;
  const ushort_t* Vg = Vbf + (size_t)(bt * H_ + h) * 64 * 512;

  // Q frags: wave covers i = w*64 + f*16 + l15, f=0..3
  short8 qf[4][2];
#pragma unroll
  for (int f = 0; f < 4; ++f) {
    const ushort_t* qrow = Qg + (size_t)(w * 64 + f * 16 + l15) * 64;
    qf[f][0] = *(const short8*)&qrow[q * 8];
    qf[f][1] = *(const short8*)&qrow[32 + q * 8];
  }

  f4 acc[4][4];
#pragma unroll
  for (int f = 0; f < 4; ++f)
#pragma unroll
    for (int dt = 0; dt < 4; ++dt) acc[f][dt] = (f4){0.f, 0.f, 0.f, 0.f};
  float lsum[4] = {0.f, 0.f, 0.f, 0.f};
  bool hi_half = (lane >= 32);
  int qh2 = (q & 1) * 2;

  for (int j0 = 0; j0 < 512; j0 += 64) {
    // K frags: A[m=j][k=d] ; V frags: A[m=d][k=j]
    short8 kf[4][2], vf[2][4];
#pragma unroll
    for (int jt = 0; jt < 4; ++jt) {
      const ushort_t* krow = Kg + (size_t)(j0 + jt * 16 + l15) * 64;
      kf[jt][0] = *(const short8*)&krow[q * 8];
      kf[jt][1] = *(const short8*)&krow[32 + q * 8];
    }
#pragma unroll
    for (int ks2 = 0; ks2 < 2; ++ks2)
#pragma unroll
      for (int dt = 0; dt < 4; ++dt)
        vf[ks2][dt] = *(const short8*)(Vg + (size_t)(dt * 16 + l15) * 512 + j0 +
                                       ks2 * 32 + q * 8);

#pragma unroll
    for (int f = 0; f < 4; ++f) {
      // S^T tiles (16j x 16i), C-layout: col=i(l15), row=j(q*4+r)
      f4 sc[4];
#pragma unroll
      for (int jt = 0; jt < 4; ++jt) {
        f4 c = {0.f, 0.f, 0.f, 0.f};
        c = __builtin_amdgcn_mfma_f32_16x16x32_bf16(kf[jt][0], qf[f][0], c, 0, 0, 0);
        c = __builtin_amdgcn_mfma_f32_16x16x32_bf16(kf[jt][1], qf[f][1], c, 0, 0, 0);
        sc[jt] = c;
      }
      // exp (no max needed) + per-lane partial sum
      float ls = 0.f;
#pragma unroll
      for (int jt = 0; jt < 4; ++jt)
#pragma unroll
        for (int r = 0; r < 4; ++r) {
          float p = __expf(sc[jt][r]);
          sc[jt][r] = p;
          ls += p;
        }
      lsum[f] += ls;

      unsigned pk01[4], pk23[4];
#pragma unroll
      for (int jt = 0; jt < 4; ++jt) {
        pk01[jt] = pack_bf16(sc[jt][0], sc[jt][1]);
        pk23[jt] = pack_bf16(sc[jt][2], sc[jt][3]);
      }
      // PV: O^T += V^T . P^T  (P^T shuffled into B-operand layout)
#pragma unroll
      for (int ks2 = 0; ks2 < 2; ++ks2) {
        union { unsigned u[4]; short8 s; } bu;
#pragma unroll
        for (int r = 0; r < 4; ++r) {
          int src = (qh2 + (r >> 1)) * 16 + l15;
          unsigned pl = (r & 1) ? pk23[ks2 * 2] : pk01[ks2 * 2];
          unsigned ph = (r & 1) ? pk23[ks2 * 2 + 1] : pk01[ks2 * 2 + 1];
          unsigned lo = __shfl(pl, src);
          unsigned hi = __shfl(ph, src);
          bu.u[r] = hi_half ? hi : lo;
        }
#pragma unroll
        for (int dt = 0; dt < 4; ++dt)
          acc[f][dt] = __builtin_amdgcn_mfma_f32_16x16x32_bf16(vf[ks2][dt], bu.s,
                                                               acc[f][dt], 0, 0, 0);
      }
    }
  }

  // epilogue: reduce l-sums, *gw, store bf16 to obfT[l][c]
  float g = gwp[bt * H_ + h];
#pragma unroll
  for (int f = 0; f < 4; ++f) {
    float ls = lsum[f];
    ls += __shfl_xor(ls, 16);
    ls += __shfl_xor(ls, 32);
    float inv = g / ls;
    int iglob = w * 64 + f * 16 + l15;
    ushort_t* ob = obfT + ((size_t)(bt * 512 + iglob)) * 512 + h * 64;
#pragma unroll
    for (int dt = 0; dt < 4; ++dt) {
      uint2 pk;
      pk.x = pack_bf16(acc[f][dt][0] * inv, acc[f][dt][1] * inv);
      pk.y = pack_bf16(acc[f][dt][2] * inv, acc[f][dt][3] * inv);
      *(uint2*)&ob[dt * 16 + q * 4] = pk;
    }
  }
}

extern "C" void kernel_launch(void* const* d_in, const int* in_sizes, int n_in,
                              void* d_out, int out_size, void* d_ws, size_t ws_size,
                              hipStream_t stream) {
  const float* e   = (const float*)d_in[0];
  const float* x   = (const float*)d_in[1];
  const float* Wq  = (const float*)d_in[2];
  const float* bq  = (const float*)d_in[3];
  const float* Wkv = (const float*)d_in[4];
  const float* bkv = (const float*)d_in[5];
  const float* Wm  = (const float*)d_in[6];
  const float* bm  = (const float*)d_in[7];
  const float* Wg1 = (const float*)d_in[8];
  const float* bg1 = (const float*)d_in[9];
  const float* Wg2 = (const float*)d_in[10];
  const float* bg2 = (const float*)d_in[11];
  float* out = (float*)d_out;

  float* ws = (float*)d_ws;
  float* pooled = ws;                  // 16384
  float* gwp    = ws + 16384;          // 256
  float* h1buf  = ws + 16640;          // 16384
  float* fb     = ws + 33024;
  ushort_t* ebfT = (ushort_t*)(fb);
  ushort_t* xbfT = (ushort_t*)(fb + 1 * 4194304);
  ushort_t* Qbf  = (ushort_t*)(fb + 2 * 4194304);
  ushort_t* Kbf  = (ushort_t*)(fb + 3 * 4194304);
  ushort_t* Vbf  = (ushort_t*)(fb + 4 * 4194304);
  ushort_t* obfT = (ushort_t*)(fb + 5 * 4194304);
  ushort_t* Wqb  = (ushort_t*)(fb + 6 * 4194304);
  ushort_t* Wkvb = Wqb + 262144;
  ushort_t* Wmb  = Wkvb + 524288;

  // zero pooled (ws is poisoned each call), then fused transpose+pool
  hipMemsetAsync(pooled, 0, 16384 * sizeof(float), stream);
  cvt_kernel<<<dim3(128), dim3(256), 0, stream>>>(Wq, Wqb);
  cvt_kernel<<<dim3(256), dim3(256), 0, stream>>>(Wkv, Wkvb);
  cvt_kernel<<<dim3(128), dim3(256), 0, stream>>>(Wm, Wmb);
  tconv_kernel<<<dim3(8, 8, 32), dim3(256), 0, stream>>>(e, ebfT, pooled);
  tconv_kernel<<<dim3(8, 8, 32), dim3(256), 0, stream>>>(x, xbfT, nullptr);
  gate1_kernel<<<dim3(128, 32), dim3(256), 0, stream>>>(pooled, Wg1, bg1, h1buf);
  gate2_kernel<<<dim3(32), dim3(256), 0, stream>>>(h1buf, Wg2, bg2, gwp);
  // q projection (normalize + 0.125) -> Qbf
  gemm_mfma<<<dim3(4, 4, 32), dim3(256), 0, stream>>>(
      Wqb, ebfT, bq, 1, nullptr, nullptr, Qbf, nullptr, gwp, 0.125f);
  // kv projection (k: normalize; v: normalize*gw) -> Kbf, Vbf
  gemm_mfma<<<dim3(4, 8, 32), dim3(256), 0, stream>>>(
      Wkvb, xbfT, bkv, 2, nullptr, nullptr, Kbf, Vbf, gwp, 1.0f);
  // attention -> obfT (one block per (h,bt))
  attn_kernel<<<dim3(H_, 32), dim3(512), 0, stream>>>(Qbf, Kbf, Vbf, gwp, obfT);
  // output projection + bias + residual -> out
  gemm_mfma<<<dim3(4, 4, 32), dim3(256), 0, stream>>>(
      Wmb, obfT, bm, 0, out, x, nullptr, nullptr, gwp, 1.0f);
}